// Round 7
// baseline (273.741 us; speedup 1.0000x reference)
//
#include <hip/hip_runtime.h>
#include <math.h>

// CRF NLL: out[b] = logZ[b] - gold[b].  B=1024, L=512, T=64.
//
// R7-R11 history: 16-batch-per-wave MFMA chains (lambda-permuted fragments)
//   verified; three memory-pipeline variants all ~131-141us. R11 counters:
//   active chain SIMDs issue ~39% (=~480 cyc/step = full instr count) ->
//   bottleneck is per-step ISSUE + dep-chain stalls at 1 wave/SIMD, NOT
//   load latency.
// R12: (1) exp OFFLOAD to producer waves (ex-gold waves, idle): producers
//   load raw logits, exp, ds_write X into double-buffered LDS; consumers
//   ds_read X. Removes 16 expf/step (~160 cyc) from the chain and moves it
//   to idle SIMDs. One lgkmcnt(0)+s_barrier per superstep (8 steps), strictly
//   matched counts; producer writes buf[(S+1)&1] while consumer reads
//   buf[S&1] (disjoint). (2) DEFERRED renorm: scale by 2^-kp computed from
//   PREVIOUS step's a[0] -> the shfl (ds_bpermute, ~100cyc) leaves the
//   critical path; f16-pack range stays ~2^-14+-10 (safe; threshold 55).
//   (3) cvt_pkrtz pack (8 instrs vs 24; RTZ bias <<1 at threshold 55).
//   (4) gold split across all 4 waves (quarter each) after the loop.
// R13: compile fix only — cvt_pkrtz returns __fp16x2, bit_cast to f16x2.

#define TDIM 64
typedef _Float16 f16;
typedef _Float16 f16x2 __attribute__((ext_vector_type(2)));
typedef _Float16 f16x8 __attribute__((ext_vector_type(8)));
typedef float    f32x4 __attribute__((ext_vector_type(4)));
typedef float    fv4   __attribute__((ext_vector_type(4)));

union B8 { f16x8 v; f16x2 p[4]; };

#define MFMA16(A, B, C) __builtin_amdgcn_mfma_f32_16x16x32_f16((A), (B), (C), 0, 0, 0)

typedef __attribute__((address_space(3))) fv4       lds_fv4;
typedef __attribute__((address_space(3))) const fv4 lds_cfv4;

// X staging: [dir][buf][slot 0..7][plane 0..3][64 lanes x 16B]
#define PLANE      1024
#define SLOT       4096
#define BUFSZ      32768
#define DIRSZ      65536
#define BITMAP_OFF 131072
#define SMEM_BYTES 132096

__device__ __forceinline__ f16x2 pkrtz(float a, float b) {
    return __builtin_bit_cast(f16x2, __builtin_amdgcn_cvt_pkrtz(a, b));
}

__device__ __forceinline__ void sync_barrier() {
    asm volatile("s_waitcnt lgkmcnt(0)" ::: "memory");
    __builtin_amdgcn_s_barrier();
}

// ---- producer: stage one chunk (8 rows) of X = exp(logits) into LDS ----
__device__ __forceinline__ const float* produce_one(
    char* cb, const float* pp, int drow, int lo)
{
    fv4 R[8][4];
    const float* p = pp;
    #pragma unroll
    for (int u = 0; u < 8; ++u) {
        R[u][0] = *(const fv4*)(p + 0);
        R[u][1] = *(const fv4*)(p + 4);
        R[u][2] = *(const fv4*)(p + 32);
        R[u][3] = *(const fv4*)(p + 36);
        p += drow;
    }
    __builtin_amdgcn_sched_barrier(0);   // keep all 32 loads issued up front
    #pragma unroll
    for (int u = 0; u < 8; ++u) {
        #pragma unroll
        for (int c = 0; c < 4; ++c) {
            fv4 x;
            #pragma unroll
            for (int r = 0; r < 4; ++r) x[r] = __expf(R[u][c][r]);
            *(lds_fv4*)(void*)(cb + u * SLOT + c * PLANE + lo) = x;
        }
    }
    return p;
}

template <int DIR>
__device__ __forceinline__ void produce(char* smem, const float* logits0,
                                        int l, int L)
{
    const int ml = l & 15, gl = l >> 4;
    const int H = L >> 1;
    char* base = smem + DIR * DIRSZ;
    const int lo = 16 * l;
    const float* pp = logits0 + ((size_t)ml * L + (DIR ? (L - 1) : 0)) * TDIM + 8 * gl;
    const int drow = DIR ? -TDIM : TDIM;
    const int NSS = H >> 3;

    pp = produce_one(base, pp, drow, lo);           // chunk 0 -> buf0
    for (int S = 0; S < NSS; ++S) {
        sync_barrier();
        if (S + 1 < NSS)
            pp = produce_one(base + ((S + 1) & 1) * BUFSZ, pp, drow, lo);
    }
}

// ---- consumer: one direction's H-step chain over 16 batches ----
// DIR=0: forward (t=0..H-1, t=0 init).  DIR=1: backward (t=L-1..H).
template <int DIR>
__device__ __forceinline__ void consume(
    char* smem, const float* __restrict__ trans,
    const int* __restrict__ mask0, int l, int L, bool masked,
    float a[16], int& kacc)
{
    const int ml = l & 15, gl = l >> 4;
    const int H = L >> 1;

    // constant A fragments: A_c,kc[m][k] = E(in=32kc+k, out=lambda(c,m))
    f16x8 Af[4][2];
    #pragma unroll
    for (int c = 0; c < 4; ++c) {
        const int mlog = 32*(c>>1) + 8*(ml>>2) + 4*(c&1) + (ml&3);
        #pragma unroll
        for (int kc = 0; kc < 2; ++kc) {
            B8 t;
            #pragma unroll
            for (int e = 0; e < 8; e += 2) {
                const int k0 = 32*kc + 8*gl + e;
                float x0, x1;
                if (DIR == 0) { x0 = trans[k0*TDIM + mlog];  x1 = trans[(k0+1)*TDIM + mlog]; }
                else          { x0 = trans[mlog*TDIM + k0];  x1 = trans[mlog*TDIM + k0 + 1]; }
                f16x2 h; h[0] = (f16)__expf(x0); h[1] = (f16)__expf(x1);
                t.p[e>>1] = h;
            }
            Af[c][kc] = t.v;
        }
    }

    // mask bitmap (cold path only)
    unsigned* mwv = (unsigned*)(smem + BITMAP_OFF + DIR * 512);
    const int t0m = DIR ? H : 0;
    const int WPB = H >> 5;
    if (masked) {
        for (int flat = l; flat < 16 * WPB; flat += 64) {
            const int mb = flat / WPB, w8 = flat - mb * WPB;
            unsigned word = 0;
            const int* mp = mask0 + (size_t)mb * L + t0m + 32 * w8;
            for (int j = 0; j < 32; ++j) word |= (mp[j] > 0 ? 1u : 0u) << j;
            mwv[flat] = word;
        }
    }

    #pragma unroll
    for (int i = 0; i < 16; ++i) a[i] = 1.f;
    kacc = 0;
    int   kp = 0;
    float sp = 1.f;

    char* base = smem + DIR * DIRSZ;
    const int lo = 16 * l;

    fv4 qc[4], qn[4];
    const int NSS = H >> 3;
    for (int S = 0; S < NSS; ++S) {
        sync_barrier();                                  // chunk S ready
        char* cb = base + (S & 1) * BUFSZ;
        #pragma unroll
        for (int c = 0; c < 4; ++c)
            qc[c] = *(lds_cfv4*)(void*)(cb + c * PLANE + lo);

        #pragma unroll
        for (int u = 0; u < 8; ++u) {
            const int st = 8 * S + u;
            if (u < 7) {
                #pragma unroll
                for (int c = 0; c < 4; ++c)
                    qn[c] = *(lds_cfv4*)(void*)(cb + (u+1)*SLOT + c*PLANE + lo);
            }

            float cand[16];
            bool init = (DIR == 0) && (S == 0) && (u == 0);
            if (init) {
                // alpha_0 = exp(logits[:,0,:]) (unscaled; sp=1, kp=0)
                #pragma unroll
                for (int c = 0; c < 4; ++c)
                    #pragma unroll
                    for (int r = 0; r < 4; ++r) cand[4*c + r] = qc[c][r];
            } else {
                float bs[16];
                if (DIR == 0) {
                    #pragma unroll
                    for (int i = 0; i < 16; ++i) bs[i] = a[i];
                } else {
                    #pragma unroll
                    for (int c = 0; c < 4; ++c)
                        #pragma unroll
                        for (int r = 0; r < 4; ++r) bs[4*c + r] = a[4*c + r] * qc[c][r];
                }
                B8 b0, b1;
                #pragma unroll
                for (int h = 0; h < 4; ++h) {
                    b0.p[h] = pkrtz(bs[2*h],     bs[2*h+1]);
                    b1.p[h] = pkrtz(bs[8 + 2*h], bs[8 + 2*h+1]);
                }
                f32x4 D0 = {0.f,0.f,0.f,0.f}, D1 = {0.f,0.f,0.f,0.f};
                f32x4 D2 = {0.f,0.f,0.f,0.f}, D3 = {0.f,0.f,0.f,0.f};
                D0 = MFMA16(Af[0][0], b0.v, D0); D0 = MFMA16(Af[0][1], b1.v, D0);
                D1 = MFMA16(Af[1][0], b0.v, D1); D1 = MFMA16(Af[1][1], b1.v, D1);
                D2 = MFMA16(Af[2][0], b0.v, D2); D2 = MFMA16(Af[2][1], b1.v, D2);
                D3 = MFMA16(Af[3][0], b0.v, D3); D3 = MFMA16(Af[3][1], b1.v, D3);
                if (DIR == 0) {   // cand = D * X * sp  (sp from PREVIOUS step)
                    #pragma unroll
                    for (int r = 0; r < 4; ++r) {
                        cand[r]      = D0[r] * (qc[0][r] * sp);
                        cand[4 + r]  = D1[r] * (qc[1][r] * sp);
                        cand[8 + r]  = D2[r] * (qc[2][r] * sp);
                        cand[12 + r] = D3[r] * (qc[3][r] * sp);
                    }
                } else {          // cand = D * sp
                    #pragma unroll
                    for (int r = 0; r < 4; ++r) {
                        cand[r] = D0[r]*sp; cand[4+r] = D1[r]*sp;
                        cand[8+r] = D2[r]*sp; cand[12+r] = D3[r]*sp;
                    }
                }
            }

            if (masked && !init) {        // cold path: gate state + kacc
                const int dt = DIR ? (H - 1 - st) : st;
                const unsigned wd = mwv[ml * WPB + (dt >> 5)];
                const int mb = (wd >> (dt & 31)) & 1;
                #pragma unroll
                for (int i = 0; i < 16; ++i) cand[i] = mb ? cand[i] : a[i];
                kacc += mb ? kp : 0;
            } else {
                kacc += kp;               // init: kp==0
            }

            #pragma unroll
            for (int i = 0; i < 16; ++i) a[i] = cand[i];

            // new pending scale from a[0] of batch ml (off critical path)
            {
                const float ref = __shfl(a[0], ml);
                const int eb = (__float_as_int(ref) >> 23) & 255;
                const bool zz = (eb == 0);
                kp = zz ? 0 : (eb - 113);                      // target 2^-14
                sp = __int_as_float(zz ? 0x3f800000u
                                       : ((unsigned)(240 - eb) << 23));
            }
            if (u < 7) {
                #pragma unroll
                for (int c = 0; c < 4; ++c) qc[c] = qn[c];
            }
        }
    }
}

__global__ __launch_bounds__(256, 1) void crf_mfma_kernel(
    const float* __restrict__ logits,  // [B, L, 64]
    const int*   __restrict__ tags,    // [B, L]
    const int*   __restrict__ mask,    // [B, L]
    const float* __restrict__ trans,   // [64, 64]
    float* __restrict__ out,           // [B]
    int L)
{
    const int tid = threadIdx.x;
    const int w   = tid >> 6;          // 0 fwd chain, 1 bwd chain, 2/3 producers
    const int l   = tid & 63;
    const int ml  = l & 15;
    const int gl  = l >> 4;
    const int bg  = blockIdx.x * 16;
    const int bi  = bg + ml;
    const int H   = L >> 1;

    __shared__ __align__(16) char smem[SMEM_BYTES];

    const float* logits0 = logits + (size_t)bg * L * TDIM;
    const int*   mask0   = mask + (size_t)bg * L;

    float a[16];
    int   kacc = 0;

    if (w < 2) {
        // fast-path detection: all-ones mask in this chain's half?
        const int t0d = (w == 0) ? 0 : H;
        bool ok = true;
        {
            const int4* m4 = (const int4*)(mask0 + (size_t)ml * L + t0d);
            #pragma unroll 4
            for (int i = 0; i < (H >> 4); ++i) {
                const int4 v = m4[gl * (H >> 4) + i];
                ok = ok && (v.x > 0) && (v.y > 0) && (v.z > 0) && (v.w > 0);
            }
        }
        const bool masked = !__all(ok ? 1 : 0);
        if (w == 0) consume<0>(smem, trans, mask0, l, L, masked, a, kacc);
        else        consume<1>(smem, trans, mask0, l, L, masked, a, kacc);
    } else {
        if (w == 2) produce<0>(smem, logits0, l, L);
        else        produce<1>(smem, logits0, l, L);
    }

    // ---------------- gold score: quarter [w*L/4, (w+1)*L/4) per wave -----
    float gs = 0.f;
    {
        const int Q  = L >> 2;
        const int t0 = w * Q;
        const int*   tb  = tags + (size_t)bi * L;
        const int*   mb  = mask + (size_t)bi * L;
        const float* lbg = logits + (size_t)bi * L * TDIM;
        #pragma unroll 4
        for (int i = 0; i < (Q >> 2); ++i) {
            const int t  = t0 + gl + 4 * i;
            const int tg = tb[t];
            const float mk = (float)mb[t];
            const float em = lbg[(size_t)t * TDIM + tg];
            const float tr = (t > 0) ? trans[tb[t-1] * TDIM + tg] : 0.f;
            gs += mk * (em + tr);
        }
        gs += __shfl_xor(gs, 16);
        gs += __shfl_xor(gs, 32);
    }

    __syncthreads();

    // staging LDS dead; carve combine buffers
    float* zfin = (float*)smem;                          // [64][16]
    float (*gpart4)[16] = (float(*)[16])(smem + 4096);   // [4][16]
    int*   kbuf = (int*)(smem + 4096 + 256);

    if (w == 1) {
        #pragma unroll
        for (int i = 0; i < 16; ++i) zfin[l * 16 + i] = a[i];
        if (l < 16) kbuf[l] = kacc;
    }
    if (l < 16) gpart4[w][l] = gs;

    __syncthreads();

    // combine: logZ = (kF+kB)ln2 + log(sum a*z)
    if (w == 0) {
        float prod = 0.f;
        #pragma unroll
        for (int i = 0; i < 16; ++i) prod += a[i] * zfin[l * 16 + i];
        prod += __shfl_xor(prod, 16);
        prod += __shfl_xor(prod, 32);
        if (l < 16) {
            const float logZ = (float)(kacc + kbuf[l]) * 0.6931471805599453f
                             + __logf(prod);
            out[bg + l] = logZ - (gpart4[0][l] + gpart4[1][l]
                                + gpart4[2][l] + gpart4[3][l]);
        }
    }
}

extern "C" void kernel_launch(void* const* d_in, const int* in_sizes, int n_in,
                              void* d_out, int out_size, void* d_ws, size_t ws_size,
                              hipStream_t stream) {
    const float* logits = (const float*)d_in[0];
    const int*   tags   = (const int*)d_in[1];
    const int*   mask   = (const int*)d_in[2];
    const float* trans  = (const float*)d_in[3];
    float* out = (float*)d_out;

    const int B = out_size;            // 1024
    const int L = in_sizes[1] / B;     // 512

    crf_mfma_kernel<<<B / 16, 256, 0, stream>>>(logits, tags, mask, trans, out, L);
}